// Round 1
// 449.521 us; speedup vs baseline: 1.3734x; 1.3734x over previous
//
#include <hip/hip_runtime.h>
#include <hip/hip_bf16.h>
#include <math.h>

// ---------------------------------------------------------------------------
// GCN GraphRegressor: 3x (linear -> gather*norm -> scatter-sum -> relu)
//                     -> segment-mean pool -> MLP head
// R13: fp16 activation storage. The aggregate passes are bound by the
//   compulsory per-XCD L2 fill of H (8 XCD x |H| bytes at ~3.6-3.9 TB/s
//   random-row fabric BW). Halving H (f32 -> fp16, 512B -> 256B rows)
//   halves FETCH_SIZE (400 -> ~205 MB) and Hout WRITE_SIZE. Gather
//   accumulates in f32; GEMMs keep the bf16 hi/lo 3-split MFMA path, so
//   only the storage rounding (rel err ~2^-12 per layer) is added.
// Keeps R12: rank-trick atomic-free CSR fill; R11: factorized norm rsq,
//   self-loop folded into aggregate, fused agg+gemm / agg+pool.
// ---------------------------------------------------------------------------

typedef float f32x4 __attribute__((ext_vector_type(4)));
typedef short s16x8 __attribute__((ext_vector_type(8)));
typedef _Float16 f16;
typedef _Float16 f16x4 __attribute__((ext_vector_type(4)));

__device__ __forceinline__ unsigned short f2bf(float x) {
  unsigned u = __float_as_uint(x);
  unsigned r = (u + 0x7FFFu + ((u >> 16) & 1u)) >> 16;
  return (unsigned short)r;
}

// ---- per-tile (1024) sums of indeg ----------------------------------------
__global__ __launch_bounds__(1024) void tile_reduce_kernel(
    const int* __restrict__ indeg, int* __restrict__ tilesum, int n) {
  __shared__ int ws[16];
  int i = blockIdx.x * 1024 + threadIdx.x;
  int v = (i < n) ? indeg[i] : 0;
  for (int off = 32; off > 0; off >>= 1) v += __shfl_down(v, off);
  int wid = threadIdx.x >> 6, lane = threadIdx.x & 63;
  if (lane == 0) ws[wid] = v;
  __syncthreads();
  if (threadIdx.x == 0) {
    int s = 0;
    for (int w = 0; w < 16; ++w) s += ws[w];
    tilesum[blockIdx.x] = s;
  }
}

// ---- per-tile scan + tile prefix; writes ptr and rsq ----------------------
__global__ __launch_bounds__(1024) void scan_emit_kernel(
    const int* __restrict__ indeg, const int* __restrict__ tilesum,
    int* __restrict__ ptr, float* __restrict__ rsq, int n, int T) {
  __shared__ int wsum[16];
  __shared__ int tilebase_s;
  int bid = blockIdx.x;
  int lane = threadIdx.x & 63, wid = threadIdx.x >> 6;
  if (threadIdx.x < 64) {
    int acc = 0;
    for (int t = threadIdx.x; t < bid; t += 64) acc += tilesum[t];
    for (int off = 32; off > 0; off >>= 1) acc += __shfl_down(acc, off);
    if (threadIdx.x == 0) tilebase_s = acc;
  }
  __syncthreads();
  int tilebase = tilebase_s;
  int i = bid * 1024 + threadIdx.x;
  int v = (i < n) ? indeg[i] : 0;
  int x = v;
  for (int off = 1; off < 64; off <<= 1) {
    int y = __shfl_up(x, off);
    if (lane >= off) x += y;
  }
  if (lane == 63) wsum[wid] = x;
  __syncthreads();
  if (threadIdx.x == 0) {
    int run = 0;
    for (int w = 0; w < 16; ++w) { int t = wsum[w]; wsum[w] = run; run += t; }
  }
  __syncthreads();
  if (i < n) {
    ptr[i] = x - v + wsum[wid] + tilebase;
    rsq[i] = 1.0f / sqrtf((float)(v + 1));  // degree incl. self-loop
  }
  if (bid == T - 1 && threadIdx.x == 1023) ptr[n] = tilebase + wsum[15] + x;
}

// ---- W split into bf16 hi/lo MFMA B-fragment layout (device body) ---------
__device__ __forceinline__ void wsplit_body(
    int blk, const float* __restrict__ W0, const float* __restrict__ W1,
    const float* __restrict__ W2, short* __restrict__ Whi, short* __restrict__ Wlo) {
  int layer = blk >> 6;
  int i = (blk & 63) * 256 + threadIdx.x;
  const float* W = (layer == 0) ? W0 : (layer == 1) ? W1 : W2;
  int j = i & 7, lane = (i >> 3) & 63, ks = (i >> 9) & 3, nt = i >> 11;
  int k = ks * 32 + (lane >> 4) * 8 + j;
  int nn = nt * 16 + (lane & 15);
  float w = W[k * 128 + nn];
  unsigned short h = f2bf(w);
  float hf = __uint_as_float(((unsigned)h) << 16);
  Whi[layer * 16384 + i] = (short)h;
  Wlo[layer * 16384 + i] = (short)f2bf(w - hf);
}

// uber0: [count_deg(returning, writes rank) | wsplit(192) | graph_bounds
//         | pool-zero]
__global__ __launch_bounds__(256) void uber0_kernel(
    const int* __restrict__ dst, int* __restrict__ indeg, int* __restrict__ rank,
    int E,
    const float* __restrict__ W0, const float* __restrict__ W1,
    const float* __restrict__ W2, short* __restrict__ Whi, short* __restrict__ Wlo,
    const int* __restrict__ batch, int* __restrict__ gptr, int n, int G,
    float* __restrict__ pool, int CD, int GBD) {
  int b = blockIdx.x;
  if (b < CD) {
    int e = b * 256 + threadIdx.x;
    if (e < E) rank[e] = atomicAdd(&indeg[dst[e]], 1);
  } else if (b < CD + 192) {
    wsplit_body(b - CD, W0, W1, W2, Whi, Wlo);
  } else if (b < CD + 192 + GBD) {
    int i = (b - CD - 192) * 256 + threadIdx.x;
    if (i < n) {
      int bb = batch[i];
      if (i == 0) {
        for (int g = 0; g <= bb; ++g) gptr[g] = 0;
      } else {
        int bp = batch[i - 1];
        for (int g = bp + 1; g <= bb; ++g) gptr[g] = i;
      }
      if (i == n - 1) {
        for (int g = bb + 1; g <= G; ++g) gptr[g] = n;
      }
    }
  } else {
    int i = (b - CD - 192 - GBD) * 256 + threadIdx.x;
    if (i * 4 < G * 128) ((float4*)pool)[i] = make_float4(0.f, 0.f, 0.f, 0.f);
  }
}

// atomic-free CSR fill: pos = ptr[d] + rank[e]  (ptr table is L2-resident)
__global__ void fill_all_kernel(const int* __restrict__ src, const int* __restrict__ dst,
                                const int* __restrict__ rank, const int* __restrict__ ptr,
                                int* __restrict__ csrc, int E) {
  int i = blockIdx.x * 256 + threadIdx.x;
  if (i < E) {
    int s = src[i], d = dst[i], r = rank[i];
    csrc[ptr[d] + r] = s;
  }
}

// gemm1: H[n,128] = (X @ W + b) * rsq[row] via 3x bf16-split MFMA; fp16 out
__global__ __launch_bounds__(256) void gemm1_kernel(
    const float* __restrict__ X, const short* __restrict__ Whi,
    const short* __restrict__ Wlo, const float* __restrict__ bias,
    const float* __restrict__ rsq, f16* __restrict__ H, int n) {
  int wave = threadIdx.x >> 6, lane = threadIdx.x & 63;
  int quad = lane >> 4, m = lane & 15;
  int mbase = blockIdx.x * 64 + wave * 16;
  int row = min(mbase + m, n - 1);
  const float* xr = X + (size_t)row * 128 + quad * 8;
  const s16x8* WH = (const s16x8*)Whi;
  const s16x8* WL = (const s16x8*)Wlo;
  f32x4 acc[8];
#pragma unroll
  for (int nt = 0; nt < 8; ++nt) acc[nt] = 0.f;
#pragma unroll
  for (int ks = 0; ks < 4; ++ks) {
    float4 xa = *(const float4*)(xr + ks * 32);
    float4 xb = *(const float4*)(xr + ks * 32 + 4);
    float xs[8] = {xa.x, xa.y, xa.z, xa.w, xb.x, xb.y, xb.z, xb.w};
    s16x8 ah, al;
#pragma unroll
    for (int j = 0; j < 8; ++j) {
      unsigned short h = f2bf(xs[j]);
      float hf = __uint_as_float(((unsigned)h) << 16);
      ah[j] = (short)h;
      al[j] = (short)f2bf(xs[j] - hf);
    }
#pragma unroll
    for (int nt = 0; nt < 8; ++nt) {
      s16x8 wh = WH[(nt * 4 + ks) * 64 + lane];
      s16x8 wl = WL[(nt * 4 + ks) * 64 + lane];
      acc[nt] = __builtin_amdgcn_mfma_f32_16x16x32_bf16(ah, wh, acc[nt], 0, 0, 0);
      acc[nt] = __builtin_amdgcn_mfma_f32_16x16x32_bf16(al, wh, acc[nt], 0, 0, 0);
      acc[nt] = __builtin_amdgcn_mfma_f32_16x16x32_bf16(ah, wl, acc[nt], 0, 0, 0);
    }
  }
  float rs[4];
#pragma unroll
  for (int r = 0; r < 4; ++r) {
    int rr = mbase + quad * 4 + r;
    rs[r] = (rr < n) ? rsq[rr] : 0.f;
  }
#pragma unroll
  for (int nt = 0; nt < 8; ++nt) {
    int col = nt * 16 + m;
    float b = bias[col];
#pragma unroll
    for (int r = 0; r < 4; ++r) {
      int rr = mbase + quad * 4 + r;
      if (rr < n) H[(size_t)rr * 128 + col] = (f16)((acc[nt][r] + b) * rs[r]);
    }
  }
}

// Aggregate core: half-wave sums one node's gathered fp16 rows + own row.
// Row = 128 x f16 = 256 B; lane hl covers chunk hl (f16x4, 8 B) -> one
// fully coalesced 256 B request per gathered row per half-wave.
// Guarded 8-deep unroll: up to 16 independent row-gathers in flight/wave.
__device__ __forceinline__ f32x4 agg_sum(
    const f16x4* __restrict__ Hc, const int* __restrict__ ptr,
    const int* __restrict__ csrc, int node, int hl) {
  int beg = ptr[node], end = ptr[node + 1];
  f32x4 a0 = __builtin_convertvector(Hc[(size_t)node * 32], f32x4);  // self
  f32x4 a1 = 0.f, a2 = 0.f, a3 = 0.f;
  f32x4 a4 = 0.f, a5 = 0.f, a6 = 0.f, a7 = 0.f;
  for (int base = beg; base < end; base += 32) {
    int m = end - base;
    if (m > 32) m = 32;
    int sl = (hl < m) ? csrc[base + hl] : 0;
    int j = 0;
    for (; j + 7 < m; j += 8) {
      int s0 = __shfl(sl, j + 0, 32), s1 = __shfl(sl, j + 1, 32);
      int s2 = __shfl(sl, j + 2, 32), s3 = __shfl(sl, j + 3, 32);
      int s4 = __shfl(sl, j + 4, 32), s5 = __shfl(sl, j + 5, 32);
      int s6 = __shfl(sl, j + 6, 32), s7 = __shfl(sl, j + 7, 32);
      f16x4 h0 = Hc[(size_t)s0 * 32];
      f16x4 h1 = Hc[(size_t)s1 * 32];
      f16x4 h2 = Hc[(size_t)s2 * 32];
      f16x4 h3 = Hc[(size_t)s3 * 32];
      f16x4 h4 = Hc[(size_t)s4 * 32];
      f16x4 h5 = Hc[(size_t)s5 * 32];
      f16x4 h6 = Hc[(size_t)s6 * 32];
      f16x4 h7 = Hc[(size_t)s7 * 32];
      a0 += __builtin_convertvector(h0, f32x4);
      a1 += __builtin_convertvector(h1, f32x4);
      a2 += __builtin_convertvector(h2, f32x4);
      a3 += __builtin_convertvector(h3, f32x4);
      a4 += __builtin_convertvector(h4, f32x4);
      a5 += __builtin_convertvector(h5, f32x4);
      a6 += __builtin_convertvector(h6, f32x4);
      a7 += __builtin_convertvector(h7, f32x4);
    }
    for (; j + 3 < m; j += 4) {
      int s0 = __shfl(sl, j + 0, 32), s1 = __shfl(sl, j + 1, 32);
      int s2 = __shfl(sl, j + 2, 32), s3 = __shfl(sl, j + 3, 32);
      f16x4 h0 = Hc[(size_t)s0 * 32];
      f16x4 h1 = Hc[(size_t)s1 * 32];
      f16x4 h2 = Hc[(size_t)s2 * 32];
      f16x4 h3 = Hc[(size_t)s3 * 32];
      a0 += __builtin_convertvector(h0, f32x4);
      a1 += __builtin_convertvector(h1, f32x4);
      a2 += __builtin_convertvector(h2, f32x4);
      a3 += __builtin_convertvector(h3, f32x4);
    }
    for (; j < m; ++j) {
      int s0 = __shfl(sl, j, 32);
      a0 += __builtin_convertvector(Hc[(size_t)s0 * 32], f32x4);
    }
  }
  return ((a0 + a1) + (a2 + a3)) + ((a4 + a5) + (a6 + a7));
}

// FUSED aggregate + next-layer GEMM (layers 2 and 3); epilogue scales by rsq.
#define LDS_STRIDE 132
__global__ __launch_bounds__(256) void agg_gemm_kernel(
    const f16* __restrict__ H, const int* __restrict__ ptr,
    const int* __restrict__ csrc, const float* __restrict__ rsq,
    const short* __restrict__ Whi, const short* __restrict__ Wlo,
    const float* __restrict__ bias, f16* __restrict__ Hout, int n) {
  __shared__ int lds[16 * LDS_STRIDE];
  int hw = threadIdx.x >> 5, hl = threadIdx.x & 31;
  int nbase = blockIdx.x * 16;
  const f16x4* Hc = (const f16x4*)H + hl;
#pragma unroll
  for (int rep = 0; rep < 2; ++rep) {
    int nl = hw + rep * 8;
    int node = nbase + nl;
    f32x4 o = 0.f;
    if (node < n) {
      f32x4 s = agg_sum(Hc, ptr, csrc, node, hl);
      float r = rsq[node];
      o.x = fmaxf(s.x * r, 0.f);
      o.y = fmaxf(s.y * r, 0.f);
      o.z = fmaxf(s.z * r, 0.f);
      o.w = fmaxf(s.w * r, 0.f);
    }
    int* dst = lds + nl * LDS_STRIDE + hl * 4;
#pragma unroll
    for (int c = 0; c < 4; ++c) {
      float v = o[c];
      unsigned short h = f2bf(v);
      float hf = __uint_as_float(((unsigned)h) << 16);
      unsigned short l = f2bf(v - hf);
      dst[c] = (int)((((unsigned)h) << 16) | l);
    }
  }
  __syncthreads();

  int wave = threadIdx.x >> 6, lane = threadIdx.x & 63;
  int quad = lane >> 4, m = lane & 15;
  const s16x8* WH = (const s16x8*)Whi;
  const s16x8* WL = (const s16x8*)Wlo;
  f32x4 acc0 = 0.f, acc1 = 0.f;
  int nt0 = wave * 2, nt1 = wave * 2 + 1;
#pragma unroll
  for (int ks = 0; ks < 4; ++ks) {
    const int* arow = lds + m * LDS_STRIDE + ks * 32 + quad * 8;
    s16x8 ah, al;
#pragma unroll
    for (int j = 0; j < 8; ++j) {
      unsigned p = (unsigned)arow[j];
      ah[j] = (short)(p >> 16);
      al[j] = (short)(p & 0xffffu);
    }
    s16x8 wh0 = WH[(nt0 * 4 + ks) * 64 + lane];
    s16x8 wl0 = WL[(nt0 * 4 + ks) * 64 + lane];
    s16x8 wh1 = WH[(nt1 * 4 + ks) * 64 + lane];
    s16x8 wl1 = WL[(nt1 * 4 + ks) * 64 + lane];
    acc0 = __builtin_amdgcn_mfma_f32_16x16x32_bf16(ah, wh0, acc0, 0, 0, 0);
    acc0 = __builtin_amdgcn_mfma_f32_16x16x32_bf16(al, wh0, acc0, 0, 0, 0);
    acc0 = __builtin_amdgcn_mfma_f32_16x16x32_bf16(ah, wl0, acc0, 0, 0, 0);
    acc1 = __builtin_amdgcn_mfma_f32_16x16x32_bf16(ah, wh1, acc1, 0, 0, 0);
    acc1 = __builtin_amdgcn_mfma_f32_16x16x32_bf16(al, wh1, acc1, 0, 0, 0);
    acc1 = __builtin_amdgcn_mfma_f32_16x16x32_bf16(ah, wl1, acc1, 0, 0, 0);
  }
  float rs[4];
#pragma unroll
  for (int r = 0; r < 4; ++r) {
    int rr = nbase + quad * 4 + r;
    rs[r] = (rr < n) ? rsq[rr] : 0.f;
  }
#pragma unroll
  for (int t = 0; t < 2; ++t) {
    int nt = wave * 2 + t;
    int col = nt * 16 + m;
    float b = bias[col];
    f32x4 a = t ? acc1 : acc0;
#pragma unroll
    for (int r = 0; r < 4; ++r) {
      int rr = nbase + quad * 4 + r;
      if (rr < n) Hout[(size_t)rr * 128 + col] = (f16)((a[r] + b) * rs[r]);
    }
  }
}

// FUSED layer-3 aggregate + segment-sum pool (block per-graph partials).
__global__ __launch_bounds__(256) void agg_pool_kernel(
    const f16* __restrict__ H, const int* __restrict__ ptr,
    const int* __restrict__ csrc, const float* __restrict__ rsq,
    const int* __restrict__ batch, float* __restrict__ pool, int n) {
  __shared__ float rows[16][128];
  __shared__ int gids[16];
  int hw = threadIdx.x >> 5, hl = threadIdx.x & 31;
  int nbase = blockIdx.x * 16;
  const f16x4* Hc = (const f16x4*)H + hl;
#pragma unroll
  for (int rep = 0; rep < 2; ++rep) {
    int nl = hw + rep * 8;
    int node = nbase + nl;
    f32x4 o = 0.f;
    if (node < n) {
      f32x4 s = agg_sum(Hc, ptr, csrc, node, hl);
      float r = rsq[node];
      o.x = fmaxf(s.x * r, 0.f);
      o.y = fmaxf(s.y * r, 0.f);
      o.z = fmaxf(s.z * r, 0.f);
      o.w = fmaxf(s.w * r, 0.f);
    }
    *(f32x4*)&rows[nl][hl * 4] = o;
    if (hl == 0) gids[nl] = (node < n) ? batch[node] : -1;
  }
  __syncthreads();
  int half = threadIdx.x >> 7;
  int ch = threadIdx.x & 127;
  float acc = 0.f;
  int curg = gids[half * 8];
  for (int i = half * 8; i < half * 8 + 8; ++i) {
    int g = gids[i];
    if (g != curg) {
      if (curg >= 0) atomicAdd(&pool[(size_t)curg * 128 + ch], acc);
      acc = 0.f;
      curg = g;
    }
    if (g >= 0) acc += rows[i][ch];
  }
  if (curg >= 0) atomicAdd(&pool[(size_t)curg * 128 + ch], acc);
}

// MLP head per graph: mean = pool/cnt (cnt from gptr), 2-layer MLP.
__global__ __launch_bounds__(128) void head_kernel(
    const float* __restrict__ pool, const int* __restrict__ gptr,
    const float* __restrict__ Wp1, const float* __restrict__ bp1,
    const float* __restrict__ Wp2, const float* __restrict__ bp2,
    float* __restrict__ out, int G) {
  int g = blockIdx.x;
  int j = threadIdx.x;
  __shared__ float ps[128];
  __shared__ float hs[128];
  int cnt = gptr[g + 1] - gptr[g];
  float inv = 1.0f / (float)max(cnt, 1);
  ps[j] = pool[(size_t)g * 128 + j] * inv;
  __syncthreads();
  float acc = bp1[j];
#pragma unroll 8
  for (int k = 0; k < 128; ++k) acc = fmaf(ps[k], Wp1[k * 128 + j], acc);
  hs[j] = fmaxf(acc, 0.f) * Wp2[j];
  __syncthreads();
  for (int off = 64; off > 0; off >>= 1) {
    if (j < off) hs[j] += hs[j + off];
    __syncthreads();
  }
  if (j == 0) out[g] = hs[0] + bp2[0];
}

extern "C" void kernel_launch(void* const* d_in, const int* in_sizes, int n_in,
                              void* d_out, int out_size, void* d_ws, size_t ws_size,
                              hipStream_t stream) {
  const float* x    = (const float*)d_in[0];
  const int*   eidx = (const int*)d_in[1];
  const int*   batch= (const int*)d_in[2];
  const float* W0 = (const float*)d_in[3];
  const float* b0 = (const float*)d_in[4];
  const float* W1 = (const float*)d_in[5];
  const float* b1 = (const float*)d_in[6];
  const float* W2 = (const float*)d_in[7];
  const float* b2 = (const float*)d_in[8];
  const float* Wp1 = (const float*)d_in[9];
  const float* bp1 = (const float*)d_in[10];
  const float* Wp2 = (const float*)d_in[11];
  const float* bp2 = (const float*)d_in[12];
  float* out = (float*)d_out;

  const int N = in_sizes[0] / 128;
  const int E = in_sizes[1] / 2;
  const int G = out_size;
  const int T = (N + 1023) / 1024;

  const int* src = eidx;
  const int* dst = eidx + E;

  char* ws = (char*)d_ws;
  size_t off = 0;
  auto alloc = [&](size_t bytes) -> void* {
    void* p = ws + off;
    off = (off + bytes + 255) & ~(size_t)255;
    return p;
  };
  int*   indeg   = (int*)  alloc((size_t)N * 4);
  int*   ptr     = (int*)  alloc((size_t)(N + 1) * 4);
  float* rsq     = (float*)alloc((size_t)N * 4);
  int*   rank    = (int*)  alloc((size_t)E * 4);
  int*   csrc    = (int*)  alloc((size_t)E * 4);
  f16*   bufA    = (f16*)  alloc((size_t)N * 128 * 2);
  f16*   bufB    = (f16*)  alloc((size_t)N * 128 * 2);
  int*   gptr    = (int*)  alloc((size_t)(G + 1) * 4);
  float* pool    = (float*)alloc((size_t)G * 128 * 4);
  int*   tilesum = (int*)  alloc((size_t)T * 4);
  short* whi     = (short*)alloc(3 * 16384 * 2);
  short* wlo     = (short*)alloc(3 * 16384 * 2);
  (void)ws_size;

  hipMemsetAsync(indeg, 0, (size_t)N * 4, stream);

  const int CD  = (E + 255) / 256;
  const int GBD = (N + 255) / 256;
  const int PZ  = (G * 128 / 4 + 255) / 256;
  uber0_kernel<<<CD + 192 + GBD + PZ, 256, 0, stream>>>(
      dst, indeg, rank, E, W0, W1, W2, whi, wlo, batch, gptr, N, G, pool,
      CD, GBD);

  tile_reduce_kernel<<<T, 1024, 0, stream>>>(indeg, tilesum, N);
  scan_emit_kernel<<<T, 1024, 0, stream>>>(indeg, tilesum, ptr, rsq, N, T);

  fill_all_kernel<<<(E + 255) / 256, 256, 0, stream>>>(src, dst, rank, ptr, csrc, E);
  gemm1_kernel<<<(N + 63) / 64, 256, 0, stream>>>(x, whi, wlo, b0, rsq, bufA, N);

  dim3 fused_grid((N + 15) / 16);
  agg_gemm_kernel<<<fused_grid, 256, 0, stream>>>(bufA, ptr, csrc, rsq,
      whi + 16384, wlo + 16384, b1, bufB, N);
  agg_gemm_kernel<<<fused_grid, 256, 0, stream>>>(bufB, ptr, csrc, rsq,
      whi + 2 * 16384, wlo + 2 * 16384, b2, bufA, N);
  agg_pool_kernel<<<fused_grid, 256, 0, stream>>>(bufA, ptr, csrc, rsq, batch, pool, N);

  head_kernel<<<G, 128, 0, stream>>>(pool, gptr, Wp1, bp1, Wp2, bp2, out, G);
}

// Round 2
// 448.598 us; speedup vs baseline: 1.3762x; 1.0021x over previous
//
#include <hip/hip_runtime.h>
#include <hip/hip_bf16.h>
#include <math.h>

// ---------------------------------------------------------------------------
// GCN GraphRegressor: 3x (linear -> gather*norm -> scatter-sum -> relu)
//                     -> segment-mean pool -> MLP head
// R14: packed-f16 gather accumulation. R13 showed the fp16 gather is no
//   longer bytes-bound (2.79 vs 4.7 TB/s marginal): the f16->f32 cvt+add
//   window between load bursts throttled outstanding requests
//   (VALUBusy 20->42%). Fix: pairwise-tree accumulate each 8/16-row group
//   in f16 (v_pk_add_f16, load feeds add directly), ONE f16x4->f32 flush
//   per group (~3x less VALU on the gather path); 16-deep load tier;
//   32-bit SADDR addressing (uniform H base + (s<<8|hl<<3) voffset).
// Keeps R13: fp16 H storage (compulsory per-XCD L2 fill halved);
// R12: rank-trick atomic-free CSR fill; R11: factorized norm rsq,
//   self-loop folded into aggregate, fused agg+gemm / agg+pool.
// ---------------------------------------------------------------------------

typedef float f32x4 __attribute__((ext_vector_type(4)));
typedef short s16x8 __attribute__((ext_vector_type(8)));
typedef _Float16 f16;
typedef _Float16 f16x4 __attribute__((ext_vector_type(4)));

__device__ __forceinline__ unsigned short f2bf(float x) {
  unsigned u = __float_as_uint(x);
  unsigned r = (u + 0x7FFFu + ((u >> 16) & 1u)) >> 16;
  return (unsigned short)r;
}

// ---- per-tile (1024) sums of indeg ----------------------------------------
__global__ __launch_bounds__(1024) void tile_reduce_kernel(
    const int* __restrict__ indeg, int* __restrict__ tilesum, int n) {
  __shared__ int ws[16];
  int i = blockIdx.x * 1024 + threadIdx.x;
  int v = (i < n) ? indeg[i] : 0;
  for (int off = 32; off > 0; off >>= 1) v += __shfl_down(v, off);
  int wid = threadIdx.x >> 6, lane = threadIdx.x & 63;
  if (lane == 0) ws[wid] = v;
  __syncthreads();
  if (threadIdx.x == 0) {
    int s = 0;
    for (int w = 0; w < 16; ++w) s += ws[w];
    tilesum[blockIdx.x] = s;
  }
}

// ---- per-tile scan + tile prefix; writes ptr and rsq ----------------------
__global__ __launch_bounds__(1024) void scan_emit_kernel(
    const int* __restrict__ indeg, const int* __restrict__ tilesum,
    int* __restrict__ ptr, float* __restrict__ rsq, int n, int T) {
  __shared__ int wsum[16];
  __shared__ int tilebase_s;
  int bid = blockIdx.x;
  int lane = threadIdx.x & 63, wid = threadIdx.x >> 6;
  if (threadIdx.x < 64) {
    int acc = 0;
    for (int t = threadIdx.x; t < bid; t += 64) acc += tilesum[t];
    for (int off = 32; off > 0; off >>= 1) acc += __shfl_down(acc, off);
    if (threadIdx.x == 0) tilebase_s = acc;
  }
  __syncthreads();
  int tilebase = tilebase_s;
  int i = bid * 1024 + threadIdx.x;
  int v = (i < n) ? indeg[i] : 0;
  int x = v;
  for (int off = 1; off < 64; off <<= 1) {
    int y = __shfl_up(x, off);
    if (lane >= off) x += y;
  }
  if (lane == 63) wsum[wid] = x;
  __syncthreads();
  if (threadIdx.x == 0) {
    int run = 0;
    for (int w = 0; w < 16; ++w) { int t = wsum[w]; wsum[w] = run; run += t; }
  }
  __syncthreads();
  if (i < n) {
    ptr[i] = x - v + wsum[wid] + tilebase;
    rsq[i] = 1.0f / sqrtf((float)(v + 1));  // degree incl. self-loop
  }
  if (bid == T - 1 && threadIdx.x == 1023) ptr[n] = tilebase + wsum[15] + x;
}

// ---- W split into bf16 hi/lo MFMA B-fragment layout (device body) ---------
__device__ __forceinline__ void wsplit_body(
    int blk, const float* __restrict__ W0, const float* __restrict__ W1,
    const float* __restrict__ W2, short* __restrict__ Whi, short* __restrict__ Wlo) {
  int layer = blk >> 6;
  int i = (blk & 63) * 256 + threadIdx.x;
  const float* W = (layer == 0) ? W0 : (layer == 1) ? W1 : W2;
  int j = i & 7, lane = (i >> 3) & 63, ks = (i >> 9) & 3, nt = i >> 11;
  int k = ks * 32 + (lane >> 4) * 8 + j;
  int nn = nt * 16 + (lane & 15);
  float w = W[k * 128 + nn];
  unsigned short h = f2bf(w);
  float hf = __uint_as_float(((unsigned)h) << 16);
  Whi[layer * 16384 + i] = (short)h;
  Wlo[layer * 16384 + i] = (short)f2bf(w - hf);
}

// uber0: [count_deg(returning, writes rank) | wsplit(192) | graph_bounds
//         | pool-zero]
__global__ __launch_bounds__(256) void uber0_kernel(
    const int* __restrict__ dst, int* __restrict__ indeg, int* __restrict__ rank,
    int E,
    const float* __restrict__ W0, const float* __restrict__ W1,
    const float* __restrict__ W2, short* __restrict__ Whi, short* __restrict__ Wlo,
    const int* __restrict__ batch, int* __restrict__ gptr, int n, int G,
    float* __restrict__ pool, int CD, int GBD) {
  int b = blockIdx.x;
  if (b < CD) {
    int e = b * 256 + threadIdx.x;
    if (e < E) rank[e] = atomicAdd(&indeg[dst[e]], 1);
  } else if (b < CD + 192) {
    wsplit_body(b - CD, W0, W1, W2, Whi, Wlo);
  } else if (b < CD + 192 + GBD) {
    int i = (b - CD - 192) * 256 + threadIdx.x;
    if (i < n) {
      int bb = batch[i];
      if (i == 0) {
        for (int g = 0; g <= bb; ++g) gptr[g] = 0;
      } else {
        int bp = batch[i - 1];
        for (int g = bp + 1; g <= bb; ++g) gptr[g] = i;
      }
      if (i == n - 1) {
        for (int g = bb + 1; g <= G; ++g) gptr[g] = n;
      }
    }
  } else {
    int i = (b - CD - 192 - GBD) * 256 + threadIdx.x;
    if (i * 4 < G * 128) ((float4*)pool)[i] = make_float4(0.f, 0.f, 0.f, 0.f);
  }
}

// atomic-free CSR fill: pos = ptr[d] + rank[e]  (ptr table is L2-resident)
__global__ void fill_all_kernel(const int* __restrict__ src, const int* __restrict__ dst,
                                const int* __restrict__ rank, const int* __restrict__ ptr,
                                int* __restrict__ csrc, int E) {
  int i = blockIdx.x * 256 + threadIdx.x;
  if (i < E) {
    int s = src[i], d = dst[i], r = rank[i];
    csrc[ptr[d] + r] = s;
  }
}

// gemm1: H[n,128] = (X @ W + b) * rsq[row] via 3x bf16-split MFMA; fp16 out
__global__ __launch_bounds__(256) void gemm1_kernel(
    const float* __restrict__ X, const short* __restrict__ Whi,
    const short* __restrict__ Wlo, const float* __restrict__ bias,
    const float* __restrict__ rsq, f16* __restrict__ H, int n) {
  int wave = threadIdx.x >> 6, lane = threadIdx.x & 63;
  int quad = lane >> 4, m = lane & 15;
  int mbase = blockIdx.x * 64 + wave * 16;
  int row = min(mbase + m, n - 1);
  const float* xr = X + (size_t)row * 128 + quad * 8;
  const s16x8* WH = (const s16x8*)Whi;
  const s16x8* WL = (const s16x8*)Wlo;
  f32x4 acc[8];
#pragma unroll
  for (int nt = 0; nt < 8; ++nt) acc[nt] = 0.f;
#pragma unroll
  for (int ks = 0; ks < 4; ++ks) {
    float4 xa = *(const float4*)(xr + ks * 32);
    float4 xb = *(const float4*)(xr + ks * 32 + 4);
    float xs[8] = {xa.x, xa.y, xa.z, xa.w, xb.x, xb.y, xb.z, xb.w};
    s16x8 ah, al;
#pragma unroll
    for (int j = 0; j < 8; ++j) {
      unsigned short h = f2bf(xs[j]);
      float hf = __uint_as_float(((unsigned)h) << 16);
      ah[j] = (short)h;
      al[j] = (short)f2bf(xs[j] - hf);
    }
#pragma unroll
    for (int nt = 0; nt < 8; ++nt) {
      s16x8 wh = WH[(nt * 4 + ks) * 64 + lane];
      s16x8 wl = WL[(nt * 4 + ks) * 64 + lane];
      acc[nt] = __builtin_amdgcn_mfma_f32_16x16x32_bf16(ah, wh, acc[nt], 0, 0, 0);
      acc[nt] = __builtin_amdgcn_mfma_f32_16x16x32_bf16(al, wh, acc[nt], 0, 0, 0);
      acc[nt] = __builtin_amdgcn_mfma_f32_16x16x32_bf16(ah, wl, acc[nt], 0, 0, 0);
    }
  }
  float rs[4];
#pragma unroll
  for (int r = 0; r < 4; ++r) {
    int rr = mbase + quad * 4 + r;
    rs[r] = (rr < n) ? rsq[rr] : 0.f;
  }
#pragma unroll
  for (int nt = 0; nt < 8; ++nt) {
    int col = nt * 16 + m;
    float b = bias[col];
#pragma unroll
    for (int r = 0; r < 4; ++r) {
      int rr = mbase + quad * 4 + r;
      if (rr < n) H[(size_t)rr * 128 + col] = (f16)((acc[nt][r] + b) * rs[r]);
    }
  }
}

// Aggregate core: half-wave sums one node's gathered fp16 rows + own row.
// Row = 128 x f16 = 256 B; lane hl covers chunk hl (f16x4, 8 B).
// 16-deep load tier (16 gathers in flight/half-wave); pairwise-tree
// packed-f16 accumulation per 8-group, one f16x4->f32x4 flush per group
// (load feeds v_pk_add_f16 directly -> short dep window between bursts).
// 32-bit SADDR addressing: uniform H base + ((s<<8)|(hl<<3)) voffset.
__device__ __forceinline__ f32x4 agg_sum(
    const f16* __restrict__ H, const int* __restrict__ ptr,
    const int* __restrict__ csrc, int node, int hl) {
  const char* Hb = (const char*)H;
  unsigned hoff = (unsigned)hl << 3;
  int beg = ptr[node], end = ptr[node + 1];
  f32x4 a = __builtin_convertvector(
      *(const f16x4*)(Hb + (((unsigned)node << 8) | hoff)), f32x4);  // self
#define ROW(s) (*(const f16x4*)(Hb + (((unsigned)(s) << 8) + hoff)))
  for (int base = beg; base < end; base += 32) {
    int m = end - base;
    if (m > 32) m = 32;
    int sl = (hl < m) ? csrc[base + hl] : 0;
    int j = 0;
    for (; j + 15 < m; j += 16) {
      int s0 = __shfl(sl, j + 0, 32), s1 = __shfl(sl, j + 1, 32);
      int s2 = __shfl(sl, j + 2, 32), s3 = __shfl(sl, j + 3, 32);
      int s4 = __shfl(sl, j + 4, 32), s5 = __shfl(sl, j + 5, 32);
      int s6 = __shfl(sl, j + 6, 32), s7 = __shfl(sl, j + 7, 32);
      int s8 = __shfl(sl, j + 8, 32), s9 = __shfl(sl, j + 9, 32);
      int sa = __shfl(sl, j + 10, 32), sb = __shfl(sl, j + 11, 32);
      int sc = __shfl(sl, j + 12, 32), sd = __shfl(sl, j + 13, 32);
      int se = __shfl(sl, j + 14, 32), sf = __shfl(sl, j + 15, 32);
      f16x4 h0 = ROW(s0), h1 = ROW(s1), h2 = ROW(s2), h3 = ROW(s3);
      f16x4 h4 = ROW(s4), h5 = ROW(s5), h6 = ROW(s6), h7 = ROW(s7);
      f16x4 h8 = ROW(s8), h9 = ROW(s9), ha = ROW(sa), hb = ROW(sb);
      f16x4 hc = ROW(sc), hd = ROW(sd), he = ROW(se), hf = ROW(sf);
      f16x4 t0 = ((h0 + h1) + (h2 + h3)) + ((h4 + h5) + (h6 + h7));
      f16x4 t1 = ((h8 + h9) + (ha + hb)) + ((hc + hd) + (he + hf));
      a += __builtin_convertvector(t0, f32x4);
      a += __builtin_convertvector(t1, f32x4);
    }
    for (; j + 7 < m; j += 8) {
      int s0 = __shfl(sl, j + 0, 32), s1 = __shfl(sl, j + 1, 32);
      int s2 = __shfl(sl, j + 2, 32), s3 = __shfl(sl, j + 3, 32);
      int s4 = __shfl(sl, j + 4, 32), s5 = __shfl(sl, j + 5, 32);
      int s6 = __shfl(sl, j + 6, 32), s7 = __shfl(sl, j + 7, 32);
      f16x4 h0 = ROW(s0), h1 = ROW(s1), h2 = ROW(s2), h3 = ROW(s3);
      f16x4 h4 = ROW(s4), h5 = ROW(s5), h6 = ROW(s6), h7 = ROW(s7);
      f16x4 t0 = ((h0 + h1) + (h2 + h3)) + ((h4 + h5) + (h6 + h7));
      a += __builtin_convertvector(t0, f32x4);
    }
    for (; j + 3 < m; j += 4) {
      int s0 = __shfl(sl, j + 0, 32), s1 = __shfl(sl, j + 1, 32);
      int s2 = __shfl(sl, j + 2, 32), s3 = __shfl(sl, j + 3, 32);
      f16x4 t0 = (ROW(s0) + ROW(s1)) + (ROW(s2) + ROW(s3));
      a += __builtin_convertvector(t0, f32x4);
    }
    for (; j < m; ++j) {
      int s0 = __shfl(sl, j, 32);
      a += __builtin_convertvector(ROW(s0), f32x4);
    }
  }
#undef ROW
  return a;
}

// FUSED aggregate + next-layer GEMM (layers 2 and 3); epilogue scales by rsq.
#define LDS_STRIDE 132
__global__ __launch_bounds__(256) void agg_gemm_kernel(
    const f16* __restrict__ H, const int* __restrict__ ptr,
    const int* __restrict__ csrc, const float* __restrict__ rsq,
    const short* __restrict__ Whi, const short* __restrict__ Wlo,
    const float* __restrict__ bias, f16* __restrict__ Hout, int n) {
  __shared__ int lds[16 * LDS_STRIDE];
  int hw = threadIdx.x >> 5, hl = threadIdx.x & 31;
  int nbase = blockIdx.x * 16;
#pragma unroll
  for (int rep = 0; rep < 2; ++rep) {
    int nl = hw + rep * 8;
    int node = nbase + nl;
    f32x4 o = 0.f;
    if (node < n) {
      f32x4 s = agg_sum(H, ptr, csrc, node, hl);
      float r = rsq[node];
      o.x = fmaxf(s.x * r, 0.f);
      o.y = fmaxf(s.y * r, 0.f);
      o.z = fmaxf(s.z * r, 0.f);
      o.w = fmaxf(s.w * r, 0.f);
    }
    int* dst = lds + nl * LDS_STRIDE + hl * 4;
#pragma unroll
    for (int c = 0; c < 4; ++c) {
      float v = o[c];
      unsigned short h = f2bf(v);
      float hf = __uint_as_float(((unsigned)h) << 16);
      unsigned short l = f2bf(v - hf);
      dst[c] = (int)((((unsigned)h) << 16) | l);
    }
  }
  __syncthreads();

  int wave = threadIdx.x >> 6, lane = threadIdx.x & 63;
  int quad = lane >> 4, m = lane & 15;
  const s16x8* WH = (const s16x8*)Whi;
  const s16x8* WL = (const s16x8*)Wlo;
  f32x4 acc0 = 0.f, acc1 = 0.f;
  int nt0 = wave * 2, nt1 = wave * 2 + 1;
#pragma unroll
  for (int ks = 0; ks < 4; ++ks) {
    const int* arow = lds + m * LDS_STRIDE + ks * 32 + quad * 8;
    s16x8 ah, al;
#pragma unroll
    for (int j = 0; j < 8; ++j) {
      unsigned p = (unsigned)arow[j];
      ah[j] = (short)(p >> 16);
      al[j] = (short)(p & 0xffffu);
    }
    s16x8 wh0 = WH[(nt0 * 4 + ks) * 64 + lane];
    s16x8 wl0 = WL[(nt0 * 4 + ks) * 64 + lane];
    s16x8 wh1 = WH[(nt1 * 4 + ks) * 64 + lane];
    s16x8 wl1 = WL[(nt1 * 4 + ks) * 64 + lane];
    acc0 = __builtin_amdgcn_mfma_f32_16x16x32_bf16(ah, wh0, acc0, 0, 0, 0);
    acc0 = __builtin_amdgcn_mfma_f32_16x16x32_bf16(al, wh0, acc0, 0, 0, 0);
    acc0 = __builtin_amdgcn_mfma_f32_16x16x32_bf16(ah, wl0, acc0, 0, 0, 0);
    acc1 = __builtin_amdgcn_mfma_f32_16x16x32_bf16(ah, wh1, acc1, 0, 0, 0);
    acc1 = __builtin_amdgcn_mfma_f32_16x16x32_bf16(al, wh1, acc1, 0, 0, 0);
    acc1 = __builtin_amdgcn_mfma_f32_16x16x32_bf16(ah, wl1, acc1, 0, 0, 0);
  }
  float rs[4];
#pragma unroll
  for (int r = 0; r < 4; ++r) {
    int rr = nbase + quad * 4 + r;
    rs[r] = (rr < n) ? rsq[rr] : 0.f;
  }
#pragma unroll
  for (int t = 0; t < 2; ++t) {
    int nt = wave * 2 + t;
    int col = nt * 16 + m;
    float b = bias[col];
    f32x4 a = t ? acc1 : acc0;
#pragma unroll
    for (int r = 0; r < 4; ++r) {
      int rr = nbase + quad * 4 + r;
      if (rr < n) Hout[(size_t)rr * 128 + col] = (f16)((a[r] + b) * rs[r]);
    }
  }
}

// FUSED layer-3 aggregate + segment-sum pool (block per-graph partials).
__global__ __launch_bounds__(256) void agg_pool_kernel(
    const f16* __restrict__ H, const int* __restrict__ ptr,
    const int* __restrict__ csrc, const float* __restrict__ rsq,
    const int* __restrict__ batch, float* __restrict__ pool, int n) {
  __shared__ float rows[16][128];
  __shared__ int gids[16];
  int hw = threadIdx.x >> 5, hl = threadIdx.x & 31;
  int nbase = blockIdx.x * 16;
#pragma unroll
  for (int rep = 0; rep < 2; ++rep) {
    int nl = hw + rep * 8;
    int node = nbase + nl;
    f32x4 o = 0.f;
    if (node < n) {
      f32x4 s = agg_sum(H, ptr, csrc, node, hl);
      float r = rsq[node];
      o.x = fmaxf(s.x * r, 0.f);
      o.y = fmaxf(s.y * r, 0.f);
      o.z = fmaxf(s.z * r, 0.f);
      o.w = fmaxf(s.w * r, 0.f);
    }
    *(f32x4*)&rows[nl][hl * 4] = o;
    if (hl == 0) gids[nl] = (node < n) ? batch[node] : -1;
  }
  __syncthreads();
  int half = threadIdx.x >> 7;
  int ch = threadIdx.x & 127;
  float acc = 0.f;
  int curg = gids[half * 8];
  for (int i = half * 8; i < half * 8 + 8; ++i) {
    int g = gids[i];
    if (g != curg) {
      if (curg >= 0) atomicAdd(&pool[(size_t)curg * 128 + ch], acc);
      acc = 0.f;
      curg = g;
    }
    if (g >= 0) acc += rows[i][ch];
  }
  if (curg >= 0) atomicAdd(&pool[(size_t)curg * 128 + ch], acc);
}

// MLP head per graph: mean = pool/cnt (cnt from gptr), 2-layer MLP.
__global__ __launch_bounds__(128) void head_kernel(
    const float* __restrict__ pool, const int* __restrict__ gptr,
    const float* __restrict__ Wp1, const float* __restrict__ bp1,
    const float* __restrict__ Wp2, const float* __restrict__ bp2,
    float* __restrict__ out, int G) {
  int g = blockIdx.x;
  int j = threadIdx.x;
  __shared__ float ps[128];
  __shared__ float hs[128];
  int cnt = gptr[g + 1] - gptr[g];
  float inv = 1.0f / (float)max(cnt, 1);
  ps[j] = pool[(size_t)g * 128 + j] * inv;
  __syncthreads();
  float acc = bp1[j];
#pragma unroll 8
  for (int k = 0; k < 128; ++k) acc = fmaf(ps[k], Wp1[k * 128 + j], acc);
  hs[j] = fmaxf(acc, 0.f) * Wp2[j];
  __syncthreads();
  for (int off = 64; off > 0; off >>= 1) {
    if (j < off) hs[j] += hs[j + off];
    __syncthreads();
  }
  if (j == 0) out[g] = hs[0] + bp2[0];
}

extern "C" void kernel_launch(void* const* d_in, const int* in_sizes, int n_in,
                              void* d_out, int out_size, void* d_ws, size_t ws_size,
                              hipStream_t stream) {
  const float* x    = (const float*)d_in[0];
  const int*   eidx = (const int*)d_in[1];
  const int*   batch= (const int*)d_in[2];
  const float* W0 = (const float*)d_in[3];
  const float* b0 = (const float*)d_in[4];
  const float* W1 = (const float*)d_in[5];
  const float* b1 = (const float*)d_in[6];
  const float* W2 = (const float*)d_in[7];
  const float* b2 = (const float*)d_in[8];
  const float* Wp1 = (const float*)d_in[9];
  const float* bp1 = (const float*)d_in[10];
  const float* Wp2 = (const float*)d_in[11];
  const float* bp2 = (const float*)d_in[12];
  float* out = (float*)d_out;

  const int N = in_sizes[0] / 128;
  const int E = in_sizes[1] / 2;
  const int G = out_size;
  const int T = (N + 1023) / 1024;

  const int* src = eidx;
  const int* dst = eidx + E;

  char* ws = (char*)d_ws;
  size_t off = 0;
  auto alloc = [&](size_t bytes) -> void* {
    void* p = ws + off;
    off = (off + bytes + 255) & ~(size_t)255;
    return p;
  };
  int*   indeg   = (int*)  alloc((size_t)N * 4);
  int*   ptr     = (int*)  alloc((size_t)(N + 1) * 4);
  float* rsq     = (float*)alloc((size_t)N * 4);
  int*   rank    = (int*)  alloc((size_t)E * 4);
  int*   csrc    = (int*)  alloc((size_t)E * 4);
  f16*   bufA    = (f16*)  alloc((size_t)N * 128 * 2);
  f16*   bufB    = (f16*)  alloc((size_t)N * 128 * 2);
  int*   gptr    = (int*)  alloc((size_t)(G + 1) * 4);
  float* pool    = (float*)alloc((size_t)G * 128 * 4);
  int*   tilesum = (int*)  alloc((size_t)T * 4);
  short* whi     = (short*)alloc(3 * 16384 * 2);
  short* wlo     = (short*)alloc(3 * 16384 * 2);
  (void)ws_size;

  hipMemsetAsync(indeg, 0, (size_t)N * 4, stream);

  const int CD  = (E + 255) / 256;
  const int GBD = (N + 255) / 256;
  const int PZ  = (G * 128 / 4 + 255) / 256;
  uber0_kernel<<<CD + 192 + GBD + PZ, 256, 0, stream>>>(
      dst, indeg, rank, E, W0, W1, W2, whi, wlo, batch, gptr, N, G, pool,
      CD, GBD);

  tile_reduce_kernel<<<T, 1024, 0, stream>>>(indeg, tilesum, N);
  scan_emit_kernel<<<T, 1024, 0, stream>>>(indeg, tilesum, ptr, rsq, N, T);

  fill_all_kernel<<<(E + 255) / 256, 256, 0, stream>>>(src, dst, rank, ptr, csrc, E);
  gemm1_kernel<<<(N + 63) / 64, 256, 0, stream>>>(x, whi, wlo, b0, rsq, bufA, N);

  dim3 fused_grid((N + 15) / 16);
  agg_gemm_kernel<<<fused_grid, 256, 0, stream>>>(bufA, ptr, csrc, rsq,
      whi + 16384, wlo + 16384, b1, bufB, N);
  agg_gemm_kernel<<<fused_grid, 256, 0, stream>>>(bufB, ptr, csrc, rsq,
      whi + 2 * 16384, wlo + 2 * 16384, b2, bufA, N);
  agg_pool_kernel<<<fused_grid, 256, 0, stream>>>(bufA, ptr, csrc, rsq, batch, pool, N);

  head_kernel<<<G, 128, 0, stream>>>(pool, gptr, Wp1, bp1, Wp2, bp2, out, G);
}

// Round 4
// 448.475 us; speedup vs baseline: 1.3766x; 1.0003x over previous
//
#include <hip/hip_runtime.h>
#include <hip/hip_bf16.h>
#include <math.h>

// ---------------------------------------------------------------------------
// GCN GraphRegressor: 3x (linear -> gather*norm -> scatter-sum -> relu)
//                     -> segment-mean pool -> MLP head
// R15b: resubmit of R15 (previous bench died in container acquisition, not
//   kernel). Preprocessing attack:
//   (1) per-XCD privatized degree counters cnt8[8][N] (count block b ->
//       copy b&7; round-robin block->XCD mapping keeps each copy's lines
//       XCD-local -> no cross-XCD atomic line migration; correctness does
//       not depend on the mapping),
//   (2) scan_emit writes per-copy exclusive prefixes (pref = ptr + prefix
//       over copies, overwrites cnt8) so CSR fill stays atomic-free:
//       csrc[pref[x][d] + rank[e]], x=(e>>8)&7,
//   (3) fill fused with gemm1 (independent, both post-scan): scatter
//       overlaps MFMA, one less launch gap.
// Keeps R14: packed-f16 tree gather accum, 16-deep bursts, SADDR addressing;
// R13: fp16 H storage; R12: rank-trick atomic-free fill; R11: factorized
//   norm rsq, self-loop in aggregate, fused agg+gemm / agg+pool.
// ---------------------------------------------------------------------------

typedef float f32x4 __attribute__((ext_vector_type(4)));
typedef short s16x8 __attribute__((ext_vector_type(8)));
typedef _Float16 f16;
typedef _Float16 f16x4 __attribute__((ext_vector_type(4)));

__device__ __forceinline__ unsigned short f2bf(float x) {
  unsigned u = __float_as_uint(x);
  unsigned r = (u + 0x7FFFu + ((u >> 16) & 1u)) >> 16;
  return (unsigned short)r;
}

// ---- per-tile (1024) sums of total indeg (sum of 8 copies) ---------------
__global__ __launch_bounds__(1024) void tile_reduce_kernel(
    const int* __restrict__ cnt8, int* __restrict__ tilesum, int n) {
  __shared__ int ws[16];
  int i = blockIdx.x * 1024 + threadIdx.x;
  int v = 0;
  if (i < n) {
#pragma unroll
    for (int c = 0; c < 8; ++c) v += cnt8[(size_t)c * n + i];
  }
  for (int off = 32; off > 0; off >>= 1) v += __shfl_down(v, off);
  int wid = threadIdx.x >> 6, lane = threadIdx.x & 63;
  if (lane == 0) ws[wid] = v;
  __syncthreads();
  if (threadIdx.x == 0) {
    int s = 0;
    for (int w = 0; w < 16; ++w) s += ws[w];
    tilesum[blockIdx.x] = s;
  }
}

// ---- per-tile scan + tile prefix; writes ptr, rsq, per-copy prefixes ------
__global__ __launch_bounds__(1024) void scan_emit_kernel(
    int* __restrict__ cnt8, const int* __restrict__ tilesum,
    int* __restrict__ ptr, float* __restrict__ rsq, int n, int T) {
  __shared__ int wsum[16];
  __shared__ int tilebase_s;
  int bid = blockIdx.x;
  int lane = threadIdx.x & 63, wid = threadIdx.x >> 6;
  if (threadIdx.x < 64) {
    int acc = 0;
    for (int t = threadIdx.x; t < bid; t += 64) acc += tilesum[t];
    for (int off = 32; off > 0; off >>= 1) acc += __shfl_down(acc, off);
    if (threadIdx.x == 0) tilebase_s = acc;
  }
  __syncthreads();
  int tilebase = tilebase_s;
  int i = bid * 1024 + threadIdx.x;
  int cc[8];
  int v = 0;
  if (i < n) {
#pragma unroll
    for (int c = 0; c < 8; ++c) { cc[c] = cnt8[(size_t)c * n + i]; v += cc[c]; }
  }
  int x = v;
  for (int off = 1; off < 64; off <<= 1) {
    int y = __shfl_up(x, off);
    if (lane >= off) x += y;
  }
  if (lane == 63) wsum[wid] = x;
  __syncthreads();
  if (threadIdx.x == 0) {
    int run = 0;
    for (int w = 0; w < 16; ++w) { int t = wsum[w]; wsum[w] = run; run += t; }
  }
  __syncthreads();
  if (i < n) {
    int p = x - v + wsum[wid] + tilebase;
    ptr[i] = p;
    rsq[i] = 1.0f / sqrtf((float)(v + 1));  // degree incl. self-loop
    int run = p;
#pragma unroll
    for (int c = 0; c < 8; ++c) {  // overwrite counters with excl. prefixes
      cnt8[(size_t)c * n + i] = run;
      run += cc[c];
    }
  }
  if (bid == T - 1 && threadIdx.x == 1023) ptr[n] = tilebase + wsum[15] + x;
}

// ---- W split into bf16 hi/lo MFMA B-fragment layout (device body) ---------
__device__ __forceinline__ void wsplit_body(
    int blk, const float* __restrict__ W0, const float* __restrict__ W1,
    const float* __restrict__ W2, short* __restrict__ Whi, short* __restrict__ Wlo) {
  int layer = blk >> 6;
  int i = (blk & 63) * 256 + threadIdx.x;
  const float* W = (layer == 0) ? W0 : (layer == 1) ? W1 : W2;
  int j = i & 7, lane = (i >> 3) & 63, ks = (i >> 9) & 3, nt = i >> 11;
  int k = ks * 32 + (lane >> 4) * 8 + j;
  int nn = nt * 16 + (lane & 15);
  float w = W[k * 128 + nn];
  unsigned short h = f2bf(w);
  float hf = __uint_as_float(((unsigned)h) << 16);
  Whi[layer * 16384 + i] = (short)h;
  Wlo[layer * 16384 + i] = (short)f2bf(w - hf);
}

// uber0: [count_deg(privatized per-XCD copies, writes rank) | wsplit(192)
//         | graph_bounds | pool-zero]
__global__ __launch_bounds__(256) void uber0_kernel(
    const int* __restrict__ dst, int* __restrict__ cnt8, int* __restrict__ rank,
    int E,
    const float* __restrict__ W0, const float* __restrict__ W1,
    const float* __restrict__ W2, short* __restrict__ Whi, short* __restrict__ Wlo,
    const int* __restrict__ batch, int* __restrict__ gptr, int n, int G,
    float* __restrict__ pool, int CD, int GBD) {
  int b = blockIdx.x;
  if (b < CD) {
    int e = b * 256 + threadIdx.x;
    if (e < E) {
      int copy = b & 7;  // round-robin block->XCD: keeps copy lines XCD-local
      rank[e] = atomicAdd(&cnt8[(size_t)copy * n + dst[e]], 1);
    }
  } else if (b < CD + 192) {
    wsplit_body(b - CD, W0, W1, W2, Whi, Wlo);
  } else if (b < CD + 192 + GBD) {
    int i = (b - CD - 192) * 256 + threadIdx.x;
    if (i < n) {
      int bb = batch[i];
      if (i == 0) {
        for (int g = 0; g <= bb; ++g) gptr[g] = 0;
      } else {
        int bp = batch[i - 1];
        for (int g = bp + 1; g <= bb; ++g) gptr[g] = i;
      }
      if (i == n - 1) {
        for (int g = bb + 1; g <= G; ++g) gptr[g] = n;
      }
    }
  } else {
    int i = (b - CD - 192 - GBD) * 256 + threadIdx.x;
    if (i * 4 < G * 128) ((float4*)pool)[i] = make_float4(0.f, 0.f, 0.f, 0.f);
  }
}

// FUSED: [atomic-free CSR fill | gemm1]  (both depend only on scan_emit)
// fill: pos = pref[copy][d] + rank[e], copy = (e>>8)&7 (matches uber0).
// gemm1: H[n,128] = (X @ W + b) * rsq[row] via 3x bf16-split MFMA; fp16 out.
__global__ __launch_bounds__(256) void fill_gemm1_kernel(
    const int* __restrict__ src, const int* __restrict__ dst,
    const int* __restrict__ rank, const int* __restrict__ pref,
    int* __restrict__ csrc, int E, int FB,
    const float* __restrict__ X, const short* __restrict__ Whi,
    const short* __restrict__ Wlo, const float* __restrict__ bias,
    const float* __restrict__ rsq, f16* __restrict__ H, int n) {
  int b = blockIdx.x;
  if (b < FB) {
    int i = b * 256 + threadIdx.x;
    if (i < E) {
      int s = src[i], d = dst[i], r = rank[i];
      int copy = (b & 7);
      csrc[pref[(size_t)copy * n + d] + r] = s;
    }
    return;
  }
  int wave = threadIdx.x >> 6, lane = threadIdx.x & 63;
  int quad = lane >> 4, m = lane & 15;
  int mbase = (b - FB) * 64 + wave * 16;
  int row = min(mbase + m, n - 1);
  const float* xr = X + (size_t)row * 128 + quad * 8;
  const s16x8* WH = (const s16x8*)Whi;
  const s16x8* WL = (const s16x8*)Wlo;
  f32x4 acc[8];
#pragma unroll
  for (int nt = 0; nt < 8; ++nt) acc[nt] = 0.f;
#pragma unroll
  for (int ks = 0; ks < 4; ++ks) {
    float4 xa = *(const float4*)(xr + ks * 32);
    float4 xb = *(const float4*)(xr + ks * 32 + 4);
    float xs[8] = {xa.x, xa.y, xa.z, xa.w, xb.x, xb.y, xb.z, xb.w};
    s16x8 ah, al;
#pragma unroll
    for (int j = 0; j < 8; ++j) {
      unsigned short h = f2bf(xs[j]);
      float hf = __uint_as_float(((unsigned)h) << 16);
      ah[j] = (short)h;
      al[j] = (short)f2bf(xs[j] - hf);
    }
#pragma unroll
    for (int nt = 0; nt < 8; ++nt) {
      s16x8 wh = WH[(nt * 4 + ks) * 64 + lane];
      s16x8 wl = WL[(nt * 4 + ks) * 64 + lane];
      acc[nt] = __builtin_amdgcn_mfma_f32_16x16x32_bf16(ah, wh, acc[nt], 0, 0, 0);
      acc[nt] = __builtin_amdgcn_mfma_f32_16x16x32_bf16(al, wh, acc[nt], 0, 0, 0);
      acc[nt] = __builtin_amdgcn_mfma_f32_16x16x32_bf16(ah, wl, acc[nt], 0, 0, 0);
    }
  }
  float rs[4];
#pragma unroll
  for (int r = 0; r < 4; ++r) {
    int rr = mbase + quad * 4 + r;
    rs[r] = (rr < n) ? rsq[rr] : 0.f;
  }
#pragma unroll
  for (int nt = 0; nt < 8; ++nt) {
    int col = nt * 16 + m;
    float bb = bias[col];
#pragma unroll
    for (int r = 0; r < 4; ++r) {
      int rr = mbase + quad * 4 + r;
      if (rr < n) H[(size_t)rr * 128 + col] = (f16)((acc[nt][r] + bb) * rs[r]);
    }
  }
}

// Aggregate core: half-wave sums one node's gathered fp16 rows + own row.
// Row = 128 x f16 = 256 B; lane hl covers chunk hl (f16x4, 8 B).
// 16-deep load tier; pairwise-tree packed-f16 accumulation per group, one
// f16x4->f32x4 flush per group; SADDR addressing (base + (s<<8|hl<<3)).
__device__ __forceinline__ f32x4 agg_sum(
    const f16* __restrict__ H, const int* __restrict__ ptr,
    const int* __restrict__ csrc, int node, int hl) {
  const char* Hb = (const char*)H;
  unsigned hoff = (unsigned)hl << 3;
  int beg = ptr[node], end = ptr[node + 1];
  f32x4 a = __builtin_convertvector(
      *(const f16x4*)(Hb + (((unsigned)node << 8) | hoff)), f32x4);  // self
#define ROW(s) (*(const f16x4*)(Hb + (((unsigned)(s) << 8) + hoff)))
  for (int base = beg; base < end; base += 32) {
    int m = end - base;
    if (m > 32) m = 32;
    int sl = (hl < m) ? csrc[base + hl] : 0;
    int j = 0;
    for (; j + 15 < m; j += 16) {
      int s0 = __shfl(sl, j + 0, 32), s1 = __shfl(sl, j + 1, 32);
      int s2 = __shfl(sl, j + 2, 32), s3 = __shfl(sl, j + 3, 32);
      int s4 = __shfl(sl, j + 4, 32), s5 = __shfl(sl, j + 5, 32);
      int s6 = __shfl(sl, j + 6, 32), s7 = __shfl(sl, j + 7, 32);
      int s8 = __shfl(sl, j + 8, 32), s9 = __shfl(sl, j + 9, 32);
      int sa = __shfl(sl, j + 10, 32), sb = __shfl(sl, j + 11, 32);
      int sc = __shfl(sl, j + 12, 32), sd = __shfl(sl, j + 13, 32);
      int se = __shfl(sl, j + 14, 32), sf = __shfl(sl, j + 15, 32);
      f16x4 h0 = ROW(s0), h1 = ROW(s1), h2 = ROW(s2), h3 = ROW(s3);
      f16x4 h4 = ROW(s4), h5 = ROW(s5), h6 = ROW(s6), h7 = ROW(s7);
      f16x4 h8 = ROW(s8), h9 = ROW(s9), ha = ROW(sa), hb = ROW(sb);
      f16x4 hc = ROW(sc), hd = ROW(sd), he = ROW(se), hf = ROW(sf);
      f16x4 t0 = ((h0 + h1) + (h2 + h3)) + ((h4 + h5) + (h6 + h7));
      f16x4 t1 = ((h8 + h9) + (ha + hb)) + ((hc + hd) + (he + hf));
      a += __builtin_convertvector(t0, f32x4);
      a += __builtin_convertvector(t1, f32x4);
    }
    for (; j + 7 < m; j += 8) {
      int s0 = __shfl(sl, j + 0, 32), s1 = __shfl(sl, j + 1, 32);
      int s2 = __shfl(sl, j + 2, 32), s3 = __shfl(sl, j + 3, 32);
      int s4 = __shfl(sl, j + 4, 32), s5 = __shfl(sl, j + 5, 32);
      int s6 = __shfl(sl, j + 6, 32), s7 = __shfl(sl, j + 7, 32);
      f16x4 h0 = ROW(s0), h1 = ROW(s1), h2 = ROW(s2), h3 = ROW(s3);
      f16x4 h4 = ROW(s4), h5 = ROW(s5), h6 = ROW(s6), h7 = ROW(s7);
      f16x4 t0 = ((h0 + h1) + (h2 + h3)) + ((h4 + h5) + (h6 + h7));
      a += __builtin_convertvector(t0, f32x4);
    }
    for (; j + 3 < m; j += 4) {
      int s0 = __shfl(sl, j + 0, 32), s1 = __shfl(sl, j + 1, 32);
      int s2 = __shfl(sl, j + 2, 32), s3 = __shfl(sl, j + 3, 32);
      f16x4 t0 = (ROW(s0) + ROW(s1)) + (ROW(s2) + ROW(s3));
      a += __builtin_convertvector(t0, f32x4);
    }
    for (; j < m; ++j) {
      int s0 = __shfl(sl, j, 32);
      a += __builtin_convertvector(ROW(s0), f32x4);
    }
  }
#undef ROW
  return a;
}

// FUSED aggregate + next-layer GEMM (layers 2 and 3); epilogue scales by rsq.
#define LDS_STRIDE 132
__global__ __launch_bounds__(256) void agg_gemm_kernel(
    const f16* __restrict__ H, const int* __restrict__ ptr,
    const int* __restrict__ csrc, const float* __restrict__ rsq,
    const short* __restrict__ Whi, const short* __restrict__ Wlo,
    const float* __restrict__ bias, f16* __restrict__ Hout, int n) {
  __shared__ int lds[16 * LDS_STRIDE];
  int hw = threadIdx.x >> 5, hl = threadIdx.x & 31;
  int nbase = blockIdx.x * 16;
#pragma unroll
  for (int rep = 0; rep < 2; ++rep) {
    int nl = hw + rep * 8;
    int node = nbase + nl;
    f32x4 o = 0.f;
    if (node < n) {
      f32x4 s = agg_sum(H, ptr, csrc, node, hl);
      float r = rsq[node];
      o.x = fmaxf(s.x * r, 0.f);
      o.y = fmaxf(s.y * r, 0.f);
      o.z = fmaxf(s.z * r, 0.f);
      o.w = fmaxf(s.w * r, 0.f);
    }
    int* dst = lds + nl * LDS_STRIDE + hl * 4;
#pragma unroll
    for (int c = 0; c < 4; ++c) {
      float v = o[c];
      unsigned short h = f2bf(v);
      float hf = __uint_as_float(((unsigned)h) << 16);
      unsigned short l = f2bf(v - hf);
      dst[c] = (int)((((unsigned)h) << 16) | l);
    }
  }
  __syncthreads();

  int wave = threadIdx.x >> 6, lane = threadIdx.x & 63;
  int quad = lane >> 4, m = lane & 15;
  const s16x8* WH = (const s16x8*)Whi;
  const s16x8* WL = (const s16x8*)Wlo;
  f32x4 acc0 = 0.f, acc1 = 0.f;
  int nt0 = wave * 2, nt1 = wave * 2 + 1;
#pragma unroll
  for (int ks = 0; ks < 4; ++ks) {
    const int* arow = lds + m * LDS_STRIDE + ks * 32 + quad * 8;
    s16x8 ah, al;
#pragma unroll
    for (int j = 0; j < 8; ++j) {
      unsigned p = (unsigned)arow[j];
      ah[j] = (short)(p >> 16);
      al[j] = (short)(p & 0xffffu);
    }
    s16x8 wh0 = WH[(nt0 * 4 + ks) * 64 + lane];
    s16x8 wl0 = WL[(nt0 * 4 + ks) * 64 + lane];
    s16x8 wh1 = WH[(nt1 * 4 + ks) * 64 + lane];
    s16x8 wl1 = WL[(nt1 * 4 + ks) * 64 + lane];
    acc0 = __builtin_amdgcn_mfma_f32_16x16x32_bf16(ah, wh0, acc0, 0, 0, 0);
    acc0 = __builtin_amdgcn_mfma_f32_16x16x32_bf16(al, wh0, acc0, 0, 0, 0);
    acc0 = __builtin_amdgcn_mfma_f32_16x16x32_bf16(ah, wl0, acc0, 0, 0, 0);
    acc1 = __builtin_amdgcn_mfma_f32_16x16x32_bf16(ah, wh1, acc1, 0, 0, 0);
    acc1 = __builtin_amdgcn_mfma_f32_16x16x32_bf16(al, wh1, acc1, 0, 0, 0);
    acc1 = __builtin_amdgcn_mfma_f32_16x16x32_bf16(ah, wl1, acc1, 0, 0, 0);
  }
  float rs[4];
#pragma unroll
  for (int r = 0; r < 4; ++r) {
    int rr = nbase + quad * 4 + r;
    rs[r] = (rr < n) ? rsq[rr] : 0.f;
  }
#pragma unroll
  for (int t = 0; t < 2; ++t) {
    int nt = wave * 2 + t;
    int col = nt * 16 + m;
    float b = bias[col];
    f32x4 a = t ? acc1 : acc0;
#pragma unroll
    for (int r = 0; r < 4; ++r) {
      int rr = nbase + quad * 4 + r;
      if (rr < n) Hout[(size_t)rr * 128 + col] = (f16)((a[r] + b) * rs[r]);
    }
  }
}

// FUSED layer-3 aggregate + segment-sum pool (block per-graph partials).
__global__ __launch_bounds__(256) void agg_pool_kernel(
    const f16* __restrict__ H, const int* __restrict__ ptr,
    const int* __restrict__ csrc, const float* __restrict__ rsq,
    const int* __restrict__ batch, float* __restrict__ pool, int n) {
  __shared__ float rows[16][128];
  __shared__ int gids[16];
  int hw = threadIdx.x >> 5, hl = threadIdx.x & 31;
  int nbase = blockIdx.x * 16;
#pragma unroll
  for (int rep = 0; rep < 2; ++rep) {
    int nl = hw + rep * 8;
    int node = nbase + nl;
    f32x4 o = 0.f;
    if (node < n) {
      f32x4 s = agg_sum(H, ptr, csrc, node, hl);
      float r = rsq[node];
      o.x = fmaxf(s.x * r, 0.f);
      o.y = fmaxf(s.y * r, 0.f);
      o.z = fmaxf(s.z * r, 0.f);
      o.w = fmaxf(s.w * r, 0.f);
    }
    *(f32x4*)&rows[nl][hl * 4] = o;
    if (hl == 0) gids[nl] = (node < n) ? batch[node] : -1;
  }
  __syncthreads();
  int half = threadIdx.x >> 7;
  int ch = threadIdx.x & 127;
  float acc = 0.f;
  int curg = gids[half * 8];
  for (int i = half * 8; i < half * 8 + 8; ++i) {
    int g = gids[i];
    if (g != curg) {
      if (curg >= 0) atomicAdd(&pool[(size_t)curg * 128 + ch], acc);
      acc = 0.f;
      curg = g;
    }
    if (g >= 0) acc += rows[i][ch];
  }
  if (curg >= 0) atomicAdd(&pool[(size_t)curg * 128 + ch], acc);
}

// MLP head per graph: mean = pool/cnt (cnt from gptr), 2-layer MLP.
__global__ __launch_bounds__(128) void head_kernel(
    const float* __restrict__ pool, const int* __restrict__ gptr,
    const float* __restrict__ Wp1, const float* __restrict__ bp1,
    const float* __restrict__ Wp2, const float* __restrict__ bp2,
    float* __restrict__ out, int G) {
  int g = blockIdx.x;
  int j = threadIdx.x;
  __shared__ float ps[128];
  __shared__ float hs[128];
  int cnt = gptr[g + 1] - gptr[g];
  float inv = 1.0f / (float)max(cnt, 1);
  ps[j] = pool[(size_t)g * 128 + j] * inv;
  __syncthreads();
  float acc = bp1[j];
#pragma unroll 8
  for (int k = 0; k < 128; ++k) acc = fmaf(ps[k], Wp1[k * 128 + j], acc);
  hs[j] = fmaxf(acc, 0.f) * Wp2[j];
  __syncthreads();
  for (int off = 64; off > 0; off >>= 1) {
    if (j < off) hs[j] += hs[j + off];
    __syncthreads();
  }
  if (j == 0) out[g] = hs[0] + bp2[0];
}

extern "C" void kernel_launch(void* const* d_in, const int* in_sizes, int n_in,
                              void* d_out, int out_size, void* d_ws, size_t ws_size,
                              hipStream_t stream) {
  const float* x    = (const float*)d_in[0];
  const int*   eidx = (const int*)d_in[1];
  const int*   batch= (const int*)d_in[2];
  const float* W0 = (const float*)d_in[3];
  const float* b0 = (const float*)d_in[4];
  const float* W1 = (const float*)d_in[5];
  const float* b1 = (const float*)d_in[6];
  const float* W2 = (const float*)d_in[7];
  const float* b2 = (const float*)d_in[8];
  const float* Wp1 = (const float*)d_in[9];
  const float* bp1 = (const float*)d_in[10];
  const float* Wp2 = (const float*)d_in[11];
  const float* bp2 = (const float*)d_in[12];
  float* out = (float*)d_out;

  const int N = in_sizes[0] / 128;
  const int E = in_sizes[1] / 2;
  const int G = out_size;
  const int T = (N + 1023) / 1024;

  const int* src = eidx;
  const int* dst = eidx + E;

  char* ws = (char*)d_ws;
  size_t off = 0;
  auto alloc = [&](size_t bytes) -> void* {
    void* p = ws + off;
    off = (off + bytes + 255) & ~(size_t)255;
    return p;
  };
  int*   cnt8    = (int*)  alloc((size_t)8 * N * 4);  // counters -> prefixes
  int*   ptr     = (int*)  alloc((size_t)(N + 1) * 4);
  float* rsq     = (float*)alloc((size_t)N * 4);
  int*   rank    = (int*)  alloc((size_t)E * 4);
  int*   csrc    = (int*)  alloc((size_t)E * 4);
  f16*   bufA    = (f16*)  alloc((size_t)N * 128 * 2);
  f16*   bufB    = (f16*)  alloc((size_t)N * 128 * 2);
  int*   gptr    = (int*)  alloc((size_t)(G + 1) * 4);
  float* pool    = (float*)alloc((size_t)G * 128 * 4);
  int*   tilesum = (int*)  alloc((size_t)T * 4);
  short* whi     = (short*)alloc(3 * 16384 * 2);
  short* wlo     = (short*)alloc(3 * 16384 * 2);
  (void)ws_size;

  hipMemsetAsync(cnt8, 0, (size_t)8 * N * 4, stream);

  const int CD  = (E + 255) / 256;
  const int GBD = (N + 255) / 256;
  const int PZ  = (G * 128 / 4 + 255) / 256;
  uber0_kernel<<<CD + 192 + GBD + PZ, 256, 0, stream>>>(
      dst, cnt8, rank, E, W0, W1, W2, whi, wlo, batch, gptr, N, G, pool,
      CD, GBD);

  tile_reduce_kernel<<<T, 1024, 0, stream>>>(cnt8, tilesum, N);
  scan_emit_kernel<<<T, 1024, 0, stream>>>(cnt8, tilesum, ptr, rsq, N, T);

  const int FB = (E + 255) / 256;
  const int GB = (N + 63) / 64;
  fill_gemm1_kernel<<<FB + GB, 256, 0, stream>>>(
      src, dst, rank, cnt8, csrc, E, FB, x, whi, wlo, b0, rsq, bufA, N);

  dim3 fused_grid((N + 15) / 16);
  agg_gemm_kernel<<<fused_grid, 256, 0, stream>>>(bufA, ptr, csrc, rsq,
      whi + 16384, wlo + 16384, b1, bufB, N);
  agg_gemm_kernel<<<fused_grid, 256, 0, stream>>>(bufB, ptr, csrc, rsq,
      whi + 2 * 16384, wlo + 2 * 16384, b2, bufA, N);
  agg_pool_kernel<<<fused_grid, 256, 0, stream>>>(bufA, ptr, csrc, rsq, batch, pool, N);

  head_kernel<<<G, 128, 0, stream>>>(pool, gptr, Wp1, bp1, Wp2, bp2, out, G);
}